// Round 11
// baseline (257.391 us; speedup 1.0000x reference)
//
#include <hip/hip_runtime.h>
#include <hip/hip_bf16.h>

#define BB 2
#define CC 64
#define HH 128
#define WW 128
#define OC 64
#define HW (HH * WW)

typedef __attribute__((ext_vector_type(8))) short bf16x8;
typedef __attribute__((ext_vector_type(4))) float f32x4;

__device__ __forceinline__ unsigned short bfbits(float f) {
    __hip_bfloat16 h = __float2bfloat16(f);
    return __builtin_bit_cast(unsigned short, h);
}
__device__ __forceinline__ float frombits(unsigned short u) {
    unsigned int v = ((unsigned int)u) << 16;
    return __builtin_bit_cast(float, v);
}
__device__ __forceinline__ int iclamp(int v, int lo, int hi) {
    return v < lo ? lo : (v > hi ? hi : v);
}

// ---------------- Wc -> bf16 pack (row-major, same layout) ----------------
__global__ __launch_bounds__(256) void wpack(const float* __restrict__ Wc,
                                             unsigned short* __restrict__ Wb)
{
    const int id = blockIdx.x * 256 + threadIdx.x;
    if (id < OC * 576) Wb[id] = bfbits(Wc[id]);
}

// ---------------- fused kernel: 16-pos strips, full-K, 4 blocks/CU regime ------
// Allocator model (R5-R10, confirmed): with __launch_bounds__(256,4) the backend
// sets the VGPR cap from LDS-allowed occupancy. 19.9KB LDS -> 8 blocks -> cap 64
// -> spills (demand ~70-85). Fix: PAD LDS to 33KB -> 4 blocks/CU -> cap 128 ->
// no spill (R5 precedent). Spend the headroom on staging MLP (unroll 8 = 32
// loads in flight). XCD-chunk swizzle gives each XCD a contiguous 32-row band.
__global__ __launch_bounds__(256, 4) void dcn_mfma16(
    const float* __restrict__ x,
    const float* __restrict__ Wp,
    const float* __restrict__ bp,
    const unsigned short* __restrict__ Wb,
    float* __restrict__ out)
{
    // [0,18432): B-buf bf16 [72 krow][16 pos][8 k]  (union: phase-0 partials fp32)
    // [18432,18720): mi  short[144]   slot = n*16+pos
    // [18720,19872): mw  ushort4[144]
    // [19872,33024): pad -- forces <=4 blocks/CU so RA targets 128 VGPR (no spill)
    __shared__ __align__(16) unsigned char smraw[33024];
    float*          part = (float*)smraw;
    unsigned short* bbuf = (unsigned short*)smraw;
    short*          mi   = (short*)(smraw + 18432);
    ushort4*        mw   = (ushort4*)(smraw + 18720);

    const int t  = threadIdx.x;
    // XCD-chunk swizzle: HW assigns physical block w to XCD w%8; remap so each
    // XCD owns a contiguous logical range (2048 = 8*256, bijective).
    const int bx = (blockIdx.x & 7) * 256 + (blockIdx.x >> 3);
    const int b  = bx >> 10;            // 1024 blocks per batch
    const int i  = (bx >> 3) & 127;
    const int j0 = (bx & 7) << 4;       // 8 strips of 16

    // ---------------- phase 0a: offset-conv partials ----------------
    {
        const int grp = t >> 4;         // 16 groups of 4 channels
        const int pp  = t & 15;
        const int j   = j0 + pp;
        float acc[18];
#pragma unroll
        for (int o = 0; o < 18; ++o) acc[o] = 0.f;
        const float* xg = x + (b * CC + grp * 4) * HW;
#pragma unroll 2
        for (int c = 0; c < 4; ++c) {
            float xv[9];
#pragma unroll
            for (int dx = 0; dx < 3; ++dx) {
                const int ii = i + dx - 1;
                const bool okx = (unsigned)ii < (unsigned)HH;
#pragma unroll
                for (int dy = 0; dy < 3; ++dy) {
                    const int jj = j + dy - 1;
                    const bool ok = okx && ((unsigned)jj < (unsigned)WW);
                    xv[dx * 3 + dy] = ok ? xg[c * HW + ii * WW + jj] : 0.f;
                }
            }
            const float* wp = Wp + (grp * 4 + c) * 9;
#pragma unroll
            for (int o = 0; o < 18; ++o) {
                const float* w = wp + o * 576;
#pragma unroll
                for (int k = 0; k < 9; ++k)
                    acc[o] = fmaf(xv[k], w[k], acc[o]);
            }
        }
#pragma unroll
        for (int o = 0; o < 18; ++o)
            part[grp * 288 + pp * 18 + o] = acc[o];
    }
    __syncthreads();

    // ---------------- phase 0b: metadata (slot = n*16+pos), t<144 ----------------
    if (t < 144) {
        const int n   = t >> 4;
        const int pos = t & 15;
        const int kx  = n / 3, ky = n - kx * 3;
        float offx = bp[n], offy = bp[9 + n];
#pragma unroll
        for (int g = 0; g < 16; ++g) {
            offx += part[g * 288 + pos * 18 + n];
            offy += part[g * 288 + pos * 18 + 9 + n];
        }
        const float px = offx + (float)(kx - 1) + (float)(i + 1);
        const float py = offy + (float)(ky - 1) + (float)(j0 + pos + 1);
        const float flx = floorf(px), fly = floorf(py);
        const float qltx = fminf(fmaxf(flx,       0.f), 129.f);
        const float qlty = fminf(fmaxf(fly,       0.f), 129.f);
        const float qrbx = fminf(fmaxf(flx + 1.f, 0.f), 129.f);
        const float qrby = fminf(fmaxf(fly + 1.f, 0.f), 129.f);
        const float pxc  = fminf(fmaxf(px, 0.f), 129.f);
        const float pyc  = fminf(fmaxf(py, 0.f), 129.f);
        const float gx0 = 1.f + (qltx - pxc), gx1 = 1.f - (qrbx - pxc);
        const float gy0 = 1.f + (qlty - pyc), gy1 = 1.f - (qrby - pyc);
        const int rx0 = (int)qltx - 1, rx1 = (int)qrbx - 1;
        const int ry0 = (int)qlty - 1, ry1 = (int)qrby - 1;
        const bool vx0 = (unsigned)rx0 < (unsigned)HH, vx1 = (unsigned)rx1 < (unsigned)HH;
        const bool vy0 = (unsigned)ry0 < (unsigned)WW, vy1 = (unsigned)ry1 < (unsigned)WW;
        const float w0 = (vx0 && vy0) ? gx0 * gy0 : 0.f;   // lt  (+0)
        const float w1 = (vx1 && vy1) ? gx1 * gy1 : 0.f;   // rb  (+129)
        const float w2 = (vx0 && vy1) ? gx0 * gy1 : 0.f;   // lb  (+1)
        const float w3 = (vx1 && vy0) ? gx1 * gy0 : 0.f;   // rt  (+128)
        mi[t] = (short)(rx0 * WW + ry0);
        mw[t] = make_ushort4(bfbits(w0), bfbits(w1), bfbits(w2), bfbits(w3));
    }
    __syncthreads();   // partials consumed; B-buf region free

    // ---------------- staging: fixed metadata per thread, channels march ----------
    // M0: (pos, n0 = sel>>1), channels half*32..+32  (32 samples)
    // M1: (pos, n=8),        channels sel*4..+4      (4 samples)
    {
        const int pos  = t & 15;
        const int sel  = t >> 4;            // 0..15
        const int n0   = sel >> 1;          // 0..7
        const int half = sel & 1;
        const float* xb = x + b * (CC * HW);

        // -- M0 --
        {
            const int slot = n0 * 16 + pos;
            const int base = (int)mi[slot];
            const ushort4 wq = mw[slot];
            const float w0 = frombits(wq.x), w1 = frombits(wq.y);
            const float w2 = frombits(wq.z), w3 = frombits(wq.w);
            const int i0 = iclamp(base,       0, HW - 1);
            const int i1 = iclamp(base + 129, 0, HW - 1);
            const int i2 = iclamp(base + 1,   0, HW - 1);
            const int i3 = iclamp(base + 128, 0, HW - 1);
            const float* p = xb + (half * 32) * HW;
            int kp = (half * 32) * 9 + n0;
#pragma unroll 8
            for (int cc = 0; cc < 32; ++cc) {
                float v = p[i0] * w0;
                v = fmaf(p[i1], w1, v);
                v = fmaf(p[i2], w2, v);
                v = fmaf(p[i3], w3, v);
                bbuf[(kp >> 3) * 128 + pos * 8 + (kp & 7)] = bfbits(v);
                p += HW;
                kp += 9;
            }
        }
        // -- M1 (tap 8) --
        {
            const int slot = 128 + pos;
            const int base = (int)mi[slot];
            const ushort4 wq = mw[slot];
            const float w0 = frombits(wq.x), w1 = frombits(wq.y);
            const float w2 = frombits(wq.z), w3 = frombits(wq.w);
            const int i0 = iclamp(base,       0, HW - 1);
            const int i1 = iclamp(base + 129, 0, HW - 1);
            const int i2 = iclamp(base + 1,   0, HW - 1);
            const int i3 = iclamp(base + 128, 0, HW - 1);
            const float* p = xb + (sel * 4) * HW;
            int kp = (sel * 4) * 9 + 8;
#pragma unroll 4
            for (int cc = 0; cc < 4; ++cc) {
                float v = p[i0] * w0;
                v = fmaf(p[i1], w1, v);
                v = fmaf(p[i2], w2, v);
                v = fmaf(p[i3], w3, v);
                bbuf[(kp >> 3) * 128 + pos * 8 + (kp & 7)] = bfbits(v);
                p += HW;
                kp += 9;
            }
        }
    }
    __syncthreads();

    // ---------------- MFMA: 18 steps, K=576, per-wave 16oc x 16pos ----------------
    const int l  = t & 63;
    const int wv = t >> 6;
    const int r  = l & 15;
    const int kb = l >> 4;
    const unsigned short* arow = Wb + (wv * 16 + r) * 576 + kb * 8;

    f32x4 acc = {0.f, 0.f, 0.f, 0.f};
#pragma unroll 6
    for (int s = 0; s < 18; ++s) {
        const bf16x8 af = *(const bf16x8*)(arow + s * 32);
        const bf16x8 bf = *(const bf16x8*)&bbuf[(s * 4 + kb) * 128 + r * 8];
        acc = __builtin_amdgcn_mfma_f32_16x16x32_bf16(af, bf, acc, 0, 0, 0);
    }

    // epilogue: col = lane&15 (pos), row = (lane>>4)*4 + reg (oc in tile)
    const int ocb = b * OC + wv * 16 + kb * 4;
#pragma unroll
    for (int reg = 0; reg < 4; ++reg) {
        out[((ocb + reg) * HH + i) * WW + j0 + r] = acc[reg];
    }
}

// ---------------- fallback: R5 kernel (proven 116us) if ws too small ----------------

struct Meta { int i0, i1, i2, i3; float w0, w1, w2, w3; };

__device__ __forceinline__ void offset_phase(
    const float* __restrict__ x, const float* __restrict__ Wp,
    const float* __restrict__ bp, float* __restrict__ smem,
    int b, int i, int j0, int t, Meta& M0, Meta& M1)
{
    {
        const int grp = t >> 5;
        const int pp  = t & 31;
        const int j   = j0 + pp;
        float part[18];
#pragma unroll
        for (int o = 0; o < 18; ++o) part[o] = 0.f;
        const float* xg = x + (b * CC + grp * 8) * HW;
        for (int c = 0; c < 8; ++c) {
            float xv[9];
#pragma unroll
            for (int dx = 0; dx < 3; ++dx) {
                const int ii = i + dx - 1;
                const bool okx = (unsigned)ii < (unsigned)HH;
#pragma unroll
                for (int dy = 0; dy < 3; ++dy) {
                    const int jj = j + dy - 1;
                    const bool ok = okx && ((unsigned)jj < (unsigned)WW);
                    xv[dx * 3 + dy] = ok ? xg[c * HW + ii * WW + jj] : 0.f;
                }
            }
            const float* wp = Wp + (grp * 8 + c) * 9;
#pragma unroll
            for (int o = 0; o < 18; ++o) {
                const float* w = wp + o * 576;
#pragma unroll
                for (int k = 0; k < 9; ++k)
                    part[o] = fmaf(xv[k], w[k], part[o]);
            }
        }
#pragma unroll
        for (int o = 0; o < 18; ++o)
            smem[grp * 576 + pp * 18 + o] = part[o];
    }
    __syncthreads();

    auto mkmeta = [&](int pos, int n) -> Meta {
        const int kx = n / 3, ky = n - kx * 3;
        float offx = bp[n], offy = bp[9 + n];
#pragma unroll
        for (int g = 0; g < 8; ++g) {
            offx += smem[g * 576 + pos * 18 + n];
            offy += smem[g * 576 + pos * 18 + 9 + n];
        }
        const float px = offx + (float)(kx - 1) + (float)(i + 1);
        const float py = offy + (float)(ky - 1) + (float)(j0 + pos + 1);
        const float flx = floorf(px), fly = floorf(py);
        const float qltx = fminf(fmaxf(flx,       0.f), 129.f);
        const float qlty = fminf(fmaxf(fly,       0.f), 129.f);
        const float qrbx = fminf(fmaxf(flx + 1.f, 0.f), 129.f);
        const float qrby = fminf(fmaxf(fly + 1.f, 0.f), 129.f);
        const float pxc  = fminf(fmaxf(px, 0.f), 129.f);
        const float pyc  = fminf(fmaxf(py, 0.f), 129.f);
        const float gx0 = 1.f + (qltx - pxc), gx1 = 1.f - (qrbx - pxc);
        const float gy0 = 1.f + (qlty - pyc), gy1 = 1.f - (qrby - pyc);
        const int rx0 = (int)qltx - 1, rx1 = (int)qrbx - 1;
        const int ry0 = (int)qlty - 1, ry1 = (int)qrby - 1;
        const bool vx0 = (unsigned)rx0 < (unsigned)HH, vx1 = (unsigned)rx1 < (unsigned)HH;
        const bool vy0 = (unsigned)ry0 < (unsigned)WW, vy1 = (unsigned)ry1 < (unsigned)WW;
        Meta M;
        M.i0 = (vx0 && vy0) ? rx0 * WW + ry0 : 0;  M.w0 = (vx0 && vy0) ? gx0 * gy0 : 0.f;
        M.i1 = (vx1 && vy1) ? rx1 * WW + ry1 : 0;  M.w1 = (vx1 && vy1) ? gx1 * gy1 : 0.f;
        M.i2 = (vx0 && vy1) ? rx0 * WW + ry1 : 0;  M.w2 = (vx0 && vy1) ? gx0 * gy1 : 0.f;
        M.i3 = (vx1 && vy0) ? rx1 * WW + ry0 : 0;  M.w3 = (vx1 && vy0) ? gx1 * gy0 : 0.f;
        return M;
    };

    M0 = mkmeta(t & 31, t >> 5);
    M1 = mkmeta(t & 31, 8);
    __syncthreads();
}

__global__ __launch_bounds__(256, 4) void dcn_mfma(
    const float* __restrict__ x,
    const float* __restrict__ Wp,
    const float* __restrict__ bp,
    const float* __restrict__ Wc,
    float* __restrict__ out)
{
    __shared__ __align__(16) unsigned char smraw[36864];
    float* smf = (float*)smraw;
    unsigned short* bbuf = (unsigned short*)smraw;

    const int t  = threadIdx.x;
    const int bx = blockIdx.x;
    const int b  = bx >> 9;
    const int i  = (bx >> 2) & 127;
    const int j0 = (bx & 3) << 5;

    Meta M0, M1;
    offset_phase(x, Wp, bp, smf, b, i, j0, t, M0, M1);

    const int pos = t & 31;
    const int n0  = t >> 5;
    const int ccb = (t >> 5) << 2;
    const float* xb = x + b * (CC * HW);

    auto stage = [&](int ch0, int dbase) {
#pragma unroll 8
        for (int cc = 0; cc < 32; ++cc) {
            const float* p = xb + (ch0 + cc) * HW;
            float v = p[M0.i0] * M0.w0;
            v = fmaf(p[M0.i1], M0.w1, v);
            v = fmaf(p[M0.i2], M0.w2, v);
            v = fmaf(p[M0.i3], M0.w3, v);
            const int kp = cc * 9 + n0;
            bbuf[dbase + ((kp >> 3) << 8) + (pos << 3) + (kp & 7)] = bfbits(v);
        }
#pragma unroll
        for (int q = 0; q < 4; ++q) {
            const int cc = ccb + q;
            const float* p = xb + (ch0 + cc) * HW;
            float v = p[M1.i0] * M1.w0;
            v = fmaf(p[M1.i1], M1.w1, v);
            v = fmaf(p[M1.i2], M1.w2, v);
            v = fmaf(p[M1.i3], M1.w3, v);
            const int kp = cc * 9 + 8;
            bbuf[dbase + ((kp >> 3) << 8) + (pos << 3) + (kp & 7)] = bfbits(v);
        }
    };

    const int w_s = __builtin_amdgcn_readfirstlane(t >> 6);
    const int l   = t & 63;
    const int r   = l & 15;
    const int kb  = l >> 4;
    const float* arow = Wc + (w_s * 16 + r) * 576 + kb * 8;

    f32x4 acc0 = {0.f, 0.f, 0.f, 0.f};
    f32x4 acc1 = {0.f, 0.f, 0.f, 0.f};

    auto mfma_chunk = [&](int cb, int dbase) {
#pragma unroll 3
        for (int s = 0; s < 9; ++s) {
            const float* ap = arow + cb + s * 32;
            const float4 alo = *(const float4*)ap;
            const float4 ahi = *(const float4*)(ap + 4);
            bf16x8 af;
            af[0] = (short)bfbits(alo.x); af[1] = (short)bfbits(alo.y);
            af[2] = (short)bfbits(alo.z); af[3] = (short)bfbits(alo.w);
            af[4] = (short)bfbits(ahi.x); af[5] = (short)bfbits(ahi.y);
            af[6] = (short)bfbits(ahi.z); af[7] = (short)bfbits(ahi.w);
            const unsigned short* bp0 = bbuf + dbase + ((s * 4 + kb) << 8) + (r << 3);
            const bf16x8 bf0 = *(const bf16x8*)bp0;
            const bf16x8 bf1 = *(const bf16x8*)(bp0 + 128);
            acc0 = __builtin_amdgcn_mfma_f32_16x16x32_bf16(af, bf0, acc0, 0, 0, 0);
            acc1 = __builtin_amdgcn_mfma_f32_16x16x32_bf16(af, bf1, acc1, 0, 0, 0);
        }
    };

    stage(0, 0);
    __syncthreads();
    mfma_chunk(0, 0);
    stage(32, 9216);
    __syncthreads();
    mfma_chunk(288, 9216);

    const int ocb = b * OC + w_s * 16;
#pragma unroll
    for (int reg = 0; reg < 4; ++reg) {
        const int oc = ocb + (l >> 4) * 4 + reg;
        float* o = out + (oc * HH + i) * WW + j0;
        o[r]      = acc0[reg];
        o[16 + r] = acc1[reg];
    }
}

extern "C" void kernel_launch(void* const* d_in, const int* in_sizes, int n_in,
                              void* d_out, int out_size, void* d_ws, size_t ws_size,
                              hipStream_t stream) {
    const float* x  = (const float*)d_in[0];
    const float* Wp = (const float*)d_in[1];
    const float* bp = (const float*)d_in[2];
    const float* Wc = (const float*)d_in[3];
    float* out = (float*)d_out;
    if (ws_size >= (size_t)(OC * 576 * 2)) {
        unsigned short* Wb = (unsigned short*)d_ws;
        wpack<<<dim3((OC * 576 + 255) / 256), dim3(256), 0, stream>>>(Wc, Wb);
        dcn_mfma16<<<dim3(BB * HH * 8), dim3(256), 0, stream>>>(x, Wp, bp, Wb, out);
    } else {
        dcn_mfma<<<dim3(BB * HH * 4), dim3(256), 0, stream>>>(x, Wp, bp, Wc, out);
    }
}

// Round 12
// 111.767 us; speedup vs baseline: 2.3029x; 2.3029x over previous
//
#include <hip/hip_runtime.h>
#include <hip/hip_bf16.h>

#define BB 2
#define CC 64
#define HH 128
#define WW 128
#define OC 64
#define HW (HH * WW)

typedef __attribute__((ext_vector_type(8))) short bf16x8;
typedef __attribute__((ext_vector_type(4))) float f32x4;

__device__ __forceinline__ unsigned short bfbits(float f) {
    __hip_bfloat16 h = __float2bfloat16(f);
    return __builtin_bit_cast(unsigned short, h);
}
__device__ __forceinline__ float frombits(unsigned short u) {
    unsigned int v = ((unsigned int)u) << 16;
    return __builtin_bit_cast(float, v);
}
__device__ __forceinline__ int iclamp(int v, int lo, int hi) {
    return v < lo ? lo : (v > hi ? hi : v);
}

// ---------------- Wc -> bf16 pack (row-major, same layout) ----------------
__global__ __launch_bounds__(256) void wpack(const float* __restrict__ Wc,
                                             unsigned short* __restrict__ Wb)
{
    const int id = blockIdx.x * 256 + threadIdx.x;
    if (id < OC * 576) Wb[id] = bfbits(Wc[id]);
}

// ---------------- fused kernel: 16-pos strips, full-K single buffer ----------------
// Toolchain VGPR-cap rule (measured R2..R11): cap = 256 / min_waves_arg,
// INDEPENDENT of LDS size.  (256,4)->64 always spilled this body (demand ~85);
// (256,8)->32 catastrophic; plain->256, occ 11%.  (256,2)->cap 128: demand fits,
// occupancy = floor(512/VGPR) waves/SIMD ~ 5 blocks/CU (LDS 19.9KB allows 8).
__global__ __launch_bounds__(256, 2) void dcn_mfma16(
    const float* __restrict__ x,
    const float* __restrict__ Wp,
    const float* __restrict__ bp,
    const unsigned short* __restrict__ Wb,
    float* __restrict__ out)
{
    // [0,18432): B-buf bf16 [72 krow][16 pos][8 k]  (union: phase-0 partials fp32)
    // [18432,18720): mi  short[144]   slot = n*16+pos
    // [18720,19872): mw  ushort4[144]
    __shared__ __align__(16) unsigned char smraw[19872];
    float*          part = (float*)smraw;
    unsigned short* bbuf = (unsigned short*)smraw;
    short*          mi   = (short*)(smraw + 18432);
    ushort4*        mw   = (ushort4*)(smraw + 18720);

    const int t  = threadIdx.x;
    // XCD-chunk swizzle (bijective on 2048): each XCD owns a contiguous band.
    const int bx = (blockIdx.x & 7) * 256 + (blockIdx.x >> 3);
    const int b  = bx >> 10;            // 1024 blocks per batch
    const int i  = (bx >> 3) & 127;
    const int j0 = (bx & 7) << 4;       // 8 strips of 16

    // ---------------- phase 0a: offset-conv partials ----------------
    {
        const int grp = t >> 4;         // 16 groups of 4 channels
        const int pp  = t & 15;
        const int j   = j0 + pp;
        float acc[18];
#pragma unroll
        for (int o = 0; o < 18; ++o) acc[o] = 0.f;
        const float* xg = x + (b * CC + grp * 4) * HW;
#pragma unroll 2
        for (int c = 0; c < 4; ++c) {
            float xv[9];
#pragma unroll
            for (int dx = 0; dx < 3; ++dx) {
                const int ii = i + dx - 1;
                const bool okx = (unsigned)ii < (unsigned)HH;
#pragma unroll
                for (int dy = 0; dy < 3; ++dy) {
                    const int jj = j + dy - 1;
                    const bool ok = okx && ((unsigned)jj < (unsigned)WW);
                    xv[dx * 3 + dy] = ok ? xg[c * HW + ii * WW + jj] : 0.f;
                }
            }
            const float* wp = Wp + (grp * 4 + c) * 9;
#pragma unroll
            for (int o = 0; o < 18; ++o) {
                const float* w = wp + o * 576;
#pragma unroll
                for (int k = 0; k < 9; ++k)
                    acc[o] = fmaf(xv[k], w[k], acc[o]);
            }
        }
#pragma unroll
        for (int o = 0; o < 18; ++o)
            part[grp * 288 + pp * 18 + o] = acc[o];
    }
    __syncthreads();

    // ---------------- phase 0b: metadata (slot = n*16+pos), t<144 ----------------
    if (t < 144) {
        const int n   = t >> 4;
        const int pos = t & 15;
        const int kx  = n / 3, ky = n - kx * 3;
        float offx = bp[n], offy = bp[9 + n];
#pragma unroll
        for (int g = 0; g < 16; ++g) {
            offx += part[g * 288 + pos * 18 + n];
            offy += part[g * 288 + pos * 18 + 9 + n];
        }
        const float px = offx + (float)(kx - 1) + (float)(i + 1);
        const float py = offy + (float)(ky - 1) + (float)(j0 + pos + 1);
        const float flx = floorf(px), fly = floorf(py);
        const float qltx = fminf(fmaxf(flx,       0.f), 129.f);
        const float qlty = fminf(fmaxf(fly,       0.f), 129.f);
        const float qrbx = fminf(fmaxf(flx + 1.f, 0.f), 129.f);
        const float qrby = fminf(fmaxf(fly + 1.f, 0.f), 129.f);
        const float pxc  = fminf(fmaxf(px, 0.f), 129.f);
        const float pyc  = fminf(fmaxf(py, 0.f), 129.f);
        const float gx0 = 1.f + (qltx - pxc), gx1 = 1.f - (qrbx - pxc);
        const float gy0 = 1.f + (qlty - pyc), gy1 = 1.f - (qrby - pyc);
        const int rx0 = (int)qltx - 1, rx1 = (int)qrbx - 1;
        const int ry0 = (int)qlty - 1, ry1 = (int)qrby - 1;
        const bool vx0 = (unsigned)rx0 < (unsigned)HH, vx1 = (unsigned)rx1 < (unsigned)HH;
        const bool vy0 = (unsigned)ry0 < (unsigned)WW, vy1 = (unsigned)ry1 < (unsigned)WW;
        const float w0 = (vx0 && vy0) ? gx0 * gy0 : 0.f;   // lt  (+0)
        const float w1 = (vx1 && vy1) ? gx1 * gy1 : 0.f;   // rb  (+129)
        const float w2 = (vx0 && vy1) ? gx0 * gy1 : 0.f;   // lb  (+1)
        const float w3 = (vx1 && vy0) ? gx1 * gy0 : 0.f;   // rt  (+128)
        mi[t] = (short)(rx0 * WW + ry0);
        mw[t] = make_ushort4(bfbits(w0), bfbits(w1), bfbits(w2), bfbits(w3));
    }
    __syncthreads();   // partials consumed; B-buf region free

    // ---------------- staging: fixed metadata per thread, channels march ----------
    // M0: (pos, n0 = sel>>1), channels half*32..+32  (32 samples)
    // M1: (pos, n=8),        channels sel*4..+4      (4 samples)
    {
        const int pos  = t & 15;
        const int sel  = t >> 4;            // 0..15
        const int n0   = sel >> 1;          // 0..7
        const int half = sel & 1;
        const float* xb = x + b * (CC * HW);

        // -- M0 --
        {
            const int slot = n0 * 16 + pos;
            const int base = (int)mi[slot];
            const ushort4 wq = mw[slot];
            const float w0 = frombits(wq.x), w1 = frombits(wq.y);
            const float w2 = frombits(wq.z), w3 = frombits(wq.w);
            const int i0 = iclamp(base,       0, HW - 1);
            const int i1 = iclamp(base + 129, 0, HW - 1);
            const int i2 = iclamp(base + 1,   0, HW - 1);
            const int i3 = iclamp(base + 128, 0, HW - 1);
            const float* p = xb + (half * 32) * HW;
            int kp = (half * 32) * 9 + n0;
#pragma unroll 8
            for (int cc = 0; cc < 32; ++cc) {
                float v = p[i0] * w0;
                v = fmaf(p[i1], w1, v);
                v = fmaf(p[i2], w2, v);
                v = fmaf(p[i3], w3, v);
                bbuf[(kp >> 3) * 128 + pos * 8 + (kp & 7)] = bfbits(v);
                p += HW;
                kp += 9;
            }
        }
        // -- M1 (tap 8) --
        {
            const int slot = 128 + pos;
            const int base = (int)mi[slot];
            const ushort4 wq = mw[slot];
            const float w0 = frombits(wq.x), w1 = frombits(wq.y);
            const float w2 = frombits(wq.z), w3 = frombits(wq.w);
            const int i0 = iclamp(base,       0, HW - 1);
            const int i1 = iclamp(base + 129, 0, HW - 1);
            const int i2 = iclamp(base + 1,   0, HW - 1);
            const int i3 = iclamp(base + 128, 0, HW - 1);
            const float* p = xb + (sel * 4) * HW;
            int kp = (sel * 4) * 9 + 8;
#pragma unroll 4
            for (int cc = 0; cc < 4; ++cc) {
                float v = p[i0] * w0;
                v = fmaf(p[i1], w1, v);
                v = fmaf(p[i2], w2, v);
                v = fmaf(p[i3], w3, v);
                bbuf[(kp >> 3) * 128 + pos * 8 + (kp & 7)] = bfbits(v);
                p += HW;
                kp += 9;
            }
        }
    }
    __syncthreads();

    // ---------------- MFMA: 18 steps, K=576, per-wave 16oc x 16pos ----------------
    const int l  = t & 63;
    const int wv = t >> 6;
    const int r  = l & 15;
    const int kb = l >> 4;
    const unsigned short* arow = Wb + (wv * 16 + r) * 576 + kb * 8;

    f32x4 acc = {0.f, 0.f, 0.f, 0.f};
#pragma unroll 6
    for (int s = 0; s < 18; ++s) {
        const bf16x8 af = *(const bf16x8*)(arow + s * 32);
        const bf16x8 bf = *(const bf16x8*)&bbuf[(s * 4 + kb) * 128 + r * 8];
        acc = __builtin_amdgcn_mfma_f32_16x16x32_bf16(af, bf, acc, 0, 0, 0);
    }

    // epilogue: col = lane&15 (pos), row = (lane>>4)*4 + reg (oc in tile)
    const int ocb = b * OC + wv * 16 + kb * 4;
#pragma unroll
    for (int reg = 0; reg < 4; ++reg) {
        out[((ocb + reg) * HH + i) * WW + j0 + r] = acc[reg];
    }
}

// ---------------- fallback: R5 kernel (proven 116us) if ws too small ----------------

struct Meta { int i0, i1, i2, i3; float w0, w1, w2, w3; };

__device__ __forceinline__ void offset_phase(
    const float* __restrict__ x, const float* __restrict__ Wp,
    const float* __restrict__ bp, float* __restrict__ smem,
    int b, int i, int j0, int t, Meta& M0, Meta& M1)
{
    {
        const int grp = t >> 5;
        const int pp  = t & 31;
        const int j   = j0 + pp;
        float part[18];
#pragma unroll
        for (int o = 0; o < 18; ++o) part[o] = 0.f;
        const float* xg = x + (b * CC + grp * 8) * HW;
        for (int c = 0; c < 8; ++c) {
            float xv[9];
#pragma unroll
            for (int dx = 0; dx < 3; ++dx) {
                const int ii = i + dx - 1;
                const bool okx = (unsigned)ii < (unsigned)HH;
#pragma unroll
                for (int dy = 0; dy < 3; ++dy) {
                    const int jj = j + dy - 1;
                    const bool ok = okx && ((unsigned)jj < (unsigned)WW);
                    xv[dx * 3 + dy] = ok ? xg[c * HW + ii * WW + jj] : 0.f;
                }
            }
            const float* wp = Wp + (grp * 8 + c) * 9;
#pragma unroll
            for (int o = 0; o < 18; ++o) {
                const float* w = wp + o * 576;
#pragma unroll
                for (int k = 0; k < 9; ++k)
                    part[o] = fmaf(xv[k], w[k], part[o]);
            }
        }
#pragma unroll
        for (int o = 0; o < 18; ++o)
            smem[grp * 576 + pp * 18 + o] = part[o];
    }
    __syncthreads();

    auto mkmeta = [&](int pos, int n) -> Meta {
        const int kx = n / 3, ky = n - kx * 3;
        float offx = bp[n], offy = bp[9 + n];
#pragma unroll
        for (int g = 0; g < 8; ++g) {
            offx += smem[g * 576 + pos * 18 + n];
            offy += smem[g * 576 + pos * 18 + 9 + n];
        }
        const float px = offx + (float)(kx - 1) + (float)(i + 1);
        const float py = offy + (float)(ky - 1) + (float)(j0 + pos + 1);
        const float flx = floorf(px), fly = floorf(py);
        const float qltx = fminf(fmaxf(flx,       0.f), 129.f);
        const float qlty = fminf(fmaxf(fly,       0.f), 129.f);
        const float qrbx = fminf(fmaxf(flx + 1.f, 0.f), 129.f);
        const float qrby = fminf(fmaxf(fly + 1.f, 0.f), 129.f);
        const float pxc  = fminf(fmaxf(px, 0.f), 129.f);
        const float pyc  = fminf(fmaxf(py, 0.f), 129.f);
        const float gx0 = 1.f + (qltx - pxc), gx1 = 1.f - (qrbx - pxc);
        const float gy0 = 1.f + (qlty - pyc), gy1 = 1.f - (qrby - pyc);
        const int rx0 = (int)qltx - 1, rx1 = (int)qrbx - 1;
        const int ry0 = (int)qlty - 1, ry1 = (int)qrby - 1;
        const bool vx0 = (unsigned)rx0 < (unsigned)HH, vx1 = (unsigned)rx1 < (unsigned)HH;
        const bool vy0 = (unsigned)ry0 < (unsigned)WW, vy1 = (unsigned)ry1 < (unsigned)WW;
        Meta M;
        M.i0 = (vx0 && vy0) ? rx0 * WW + ry0 : 0;  M.w0 = (vx0 && vy0) ? gx0 * gy0 : 0.f;
        M.i1 = (vx1 && vy1) ? rx1 * WW + ry1 : 0;  M.w1 = (vx1 && vy1) ? gx1 * gy1 : 0.f;
        M.i2 = (vx0 && vy1) ? rx0 * WW + ry1 : 0;  M.w2 = (vx0 && vy1) ? gx0 * gy1 : 0.f;
        M.i3 = (vx1 && vy0) ? rx1 * WW + ry0 : 0;  M.w3 = (vx1 && vy0) ? gx1 * gy0 : 0.f;
        return M;
    };

    M0 = mkmeta(t & 31, t >> 5);
    M1 = mkmeta(t & 31, 8);
    __syncthreads();
}

__global__ __launch_bounds__(256, 4) void dcn_mfma(
    const float* __restrict__ x,
    const float* __restrict__ Wp,
    const float* __restrict__ bp,
    const float* __restrict__ Wc,
    float* __restrict__ out)
{
    __shared__ __align__(16) unsigned char smraw[36864];
    float* smf = (float*)smraw;
    unsigned short* bbuf = (unsigned short*)smraw;

    const int t  = threadIdx.x;
    const int bx = blockIdx.x;
    const int b  = bx >> 9;
    const int i  = (bx >> 2) & 127;
    const int j0 = (bx & 3) << 5;

    Meta M0, M1;
    offset_phase(x, Wp, bp, smf, b, i, j0, t, M0, M1);

    const int pos = t & 31;
    const int n0  = t >> 5;
    const int ccb = (t >> 5) << 2;
    const float* xb = x + b * (CC * HW);

    auto stage = [&](int ch0, int dbase) {
#pragma unroll 8
        for (int cc = 0; cc < 32; ++cc) {
            const float* p = xb + (ch0 + cc) * HW;
            float v = p[M0.i0] * M0.w0;
            v = fmaf(p[M0.i1], M0.w1, v);
            v = fmaf(p[M0.i2], M0.w2, v);
            v = fmaf(p[M0.i3], M0.w3, v);
            const int kp = cc * 9 + n0;
            bbuf[dbase + ((kp >> 3) << 8) + (pos << 3) + (kp & 7)] = bfbits(v);
        }
#pragma unroll
        for (int q = 0; q < 4; ++q) {
            const int cc = ccb + q;
            const float* p = xb + (ch0 + cc) * HW;
            float v = p[M1.i0] * M1.w0;
            v = fmaf(p[M1.i1], M1.w1, v);
            v = fmaf(p[M1.i2], M1.w2, v);
            v = fmaf(p[M1.i3], M1.w3, v);
            const int kp = cc * 9 + 8;
            bbuf[dbase + ((kp >> 3) << 8) + (pos << 3) + (kp & 7)] = bfbits(v);
        }
    };

    const int w_s = __builtin_amdgcn_readfirstlane(t >> 6);
    const int l   = t & 63;
    const int r   = l & 15;
    const int kb  = l >> 4;
    const float* arow = Wc + (w_s * 16 + r) * 576 + kb * 8;

    f32x4 acc0 = {0.f, 0.f, 0.f, 0.f};
    f32x4 acc1 = {0.f, 0.f, 0.f, 0.f};

    auto mfma_chunk = [&](int cb, int dbase) {
#pragma unroll 3
        for (int s = 0; s < 9; ++s) {
            const float* ap = arow + cb + s * 32;
            const float4 alo = *(const float4*)ap;
            const float4 ahi = *(const float4*)(ap + 4);
            bf16x8 af;
            af[0] = (short)bfbits(alo.x); af[1] = (short)bfbits(alo.y);
            af[2] = (short)bfbits(alo.z); af[3] = (short)bfbits(alo.w);
            af[4] = (short)bfbits(ahi.x); af[5] = (short)bfbits(ahi.y);
            af[6] = (short)bfbits(ahi.z); af[7] = (short)bfbits(ahi.w);
            const unsigned short* bp0 = bbuf + dbase + ((s * 4 + kb) << 8) + (r << 3);
            const bf16x8 bf0 = *(const bf16x8*)bp0;
            const bf16x8 bf1 = *(const bf16x8*)(bp0 + 128);
            acc0 = __builtin_amdgcn_mfma_f32_16x16x32_bf16(af, bf0, acc0, 0, 0, 0);
            acc1 = __builtin_amdgcn_mfma_f32_16x16x32_bf16(af, bf1, acc1, 0, 0, 0);
        }
    };

    stage(0, 0);
    __syncthreads();
    mfma_chunk(0, 0);
    stage(32, 9216);
    __syncthreads();
    mfma_chunk(288, 9216);

    const int ocb = b * OC + w_s * 16;
#pragma unroll
    for (int reg = 0; reg < 4; ++reg) {
        const int oc = ocb + (l >> 4) * 4 + reg;
        float* o = out + (oc * HH + i) * WW + j0;
        o[r]      = acc0[reg];
        o[16 + r] = acc1[reg];
    }
}

extern "C" void kernel_launch(void* const* d_in, const int* in_sizes, int n_in,
                              void* d_out, int out_size, void* d_ws, size_t ws_size,
                              hipStream_t stream) {
    const float* x  = (const float*)d_in[0];
    const float* Wp = (const float*)d_in[1];
    const float* bp = (const float*)d_in[2];
    const float* Wc = (const float*)d_in[3];
    float* out = (float*)d_out;
    if (ws_size >= (size_t)(OC * 576 * 2)) {
        unsigned short* Wb = (unsigned short*)d_ws;
        wpack<<<dim3((OC * 576 + 255) / 256), dim3(256), 0, stream>>>(Wc, Wb);
        dcn_mfma16<<<dim3(BB * HH * 8), dim3(256), 0, stream>>>(x, Wp, bp, Wb, out);
    } else {
        dcn_mfma<<<dim3(BB * HH * 4), dim3(256), 0, stream>>>(x, Wp, bp, Wc, out);
    }
}

// Round 13
// 98.875 us; speedup vs baseline: 2.6032x; 1.1304x over previous
//
#include <hip/hip_runtime.h>
#include <hip/hip_bf16.h>

#define BB 2
#define CC 64
#define HH 128
#define WW 128
#define OC 64
#define HW (HH * WW)

typedef __attribute__((ext_vector_type(8))) short bf16x8;
typedef __attribute__((ext_vector_type(4))) float f32x4;

__device__ __forceinline__ unsigned short bfbits(float f) {
    __hip_bfloat16 h = __float2bfloat16(f);
    return __builtin_bit_cast(unsigned short, h);
}
__device__ __forceinline__ float frombits(unsigned short u) {
    unsigned int v = ((unsigned int)u) << 16;
    return __builtin_bit_cast(float, v);
}
__device__ __forceinline__ int iclamp(int v, int lo, int hi) {
    return v < lo ? lo : (v > hi ? hi : v);
}

// ---------------- Wc -> bf16 A-fragment pack ----------------
// K-order k'' = n*64 + c. Fragment order: idx = ((a*4 + m)*16 + r)*8 + j
// where a = k''-octet (0..71), m = oc-tile, r = row in tile, j = k within octet.
// Lane (r,kb) of tile m at step s reads 16B at (s*4+kb)*512 + m*128 + r*8.
__global__ __launch_bounds__(256) void wpack2(const float* __restrict__ Wc,
                                              unsigned short* __restrict__ Wb3)
{
    const int idx = blockIdx.x * 256 + threadIdx.x;
    if (idx < OC * 576) {
        const int j = idx & 7;
        const int r = (idx >> 3) & 15;
        const int m = (idx >> 7) & 3;
        const int a = idx >> 9;
        const int n = a >> 3;
        const int c = (a & 7) * 8 + j;
        const int oc = m * 16 + r;
        Wb3[idx] = bfbits(Wc[oc * 576 + c * 9 + n]);
    }
}

// ---------------- main kernel: cooperative offsets, independent wave GEMM ------
// Block = 32-pos segment: phase0 (offset conv + metadata) cooperative, then
// 4 waves = 2 strips x 2 K-halves run gather->fragment->MFMA with NO barriers
// (B built directly in registers; A from Wb3 fragment pack). K-halves reduced
// through LDS at the end. VGPR cap 128 via (256,2) [cap = 256/min_waves, R2-R11].
__global__ __launch_bounds__(256, 2) void dcn_wave(
    const float* __restrict__ x,
    const float* __restrict__ Wp,
    const float* __restrict__ bp,
    const unsigned short* __restrict__ Wb3,
    float* __restrict__ out)
{
    // [0,18432): part fp32 [8 grp][32 pos][18]   (union: reduction scratch)
    // [18432,19008): mi  short[288]   slot = n*32 + pos
    // [19008,21312): mw  ushort4[288]
    __shared__ __align__(16) unsigned char smraw[21312];
    float*          part = (float*)smraw;
    short*          mi   = (short*)(smraw + 18432);
    ushort4*        mw   = (ushort4*)(smraw + 19008);

    const int t   = threadIdx.x;
    const int bxr = (blockIdx.x & 7) * 128 + (blockIdx.x >> 3);  // XCD chunk swizzle
    const int b   = bxr >> 9;
    const int i   = (bxr >> 2) & 127;
    const int j0  = (bxr & 3) << 5;      // 32-pos segment base

    // ---------------- phase 0a: offset-conv partials (R3-verified) ----------------
    {
        const int grp = t >> 5;          // 8 groups of 8 channels
        const int pp  = t & 31;
        const int j   = j0 + pp;
        float acc[18];
#pragma unroll
        for (int o = 0; o < 18; ++o) acc[o] = 0.f;
        const float* xg = x + (b * CC + grp * 8) * HW;
        for (int c = 0; c < 8; ++c) {
            float xv[9];
#pragma unroll
            for (int dx = 0; dx < 3; ++dx) {
                const int ii = i + dx - 1;
                const bool okx = (unsigned)ii < (unsigned)HH;
#pragma unroll
                for (int dy = 0; dy < 3; ++dy) {
                    const int jj = j + dy - 1;
                    const bool ok = okx && ((unsigned)jj < (unsigned)WW);
                    xv[dx * 3 + dy] = ok ? xg[c * HW + ii * WW + jj] : 0.f;
                }
            }
            const float* wp = Wp + (grp * 8 + c) * 9;
#pragma unroll
            for (int o = 0; o < 18; ++o) {
                const float* w = wp + o * 576;
#pragma unroll
                for (int k = 0; k < 9; ++k)
                    acc[o] = fmaf(xv[k], w[k], acc[o]);
            }
        }
#pragma unroll
        for (int o = 0; o < 18; ++o)
            part[grp * 576 + pp * 18 + o] = acc[o];
    }
    __syncthreads();

    // ---------------- phase 0b: metadata, 288 slots ----------------
    {
        auto mkmeta = [&](int slot) {
            const int n   = slot >> 5;
            const int pos = slot & 31;
            const int kx  = n / 3, ky = n - kx * 3;
            float offx = bp[n], offy = bp[9 + n];
#pragma unroll
            for (int g = 0; g < 8; ++g) {
                offx += part[g * 576 + pos * 18 + n];
                offy += part[g * 576 + pos * 18 + 9 + n];
            }
            const float px = offx + (float)(kx - 1) + (float)(i + 1);
            const float py = offy + (float)(ky - 1) + (float)(j0 + pos + 1);
            const float flx = floorf(px), fly = floorf(py);
            const float qltx = fminf(fmaxf(flx,       0.f), 129.f);
            const float qlty = fminf(fmaxf(fly,       0.f), 129.f);
            const float qrbx = fminf(fmaxf(flx + 1.f, 0.f), 129.f);
            const float qrby = fminf(fmaxf(fly + 1.f, 0.f), 129.f);
            const float pxc  = fminf(fmaxf(px, 0.f), 129.f);
            const float pyc  = fminf(fmaxf(py, 0.f), 129.f);
            const float gx0 = 1.f + (qltx - pxc), gx1 = 1.f - (qrbx - pxc);
            const float gy0 = 1.f + (qlty - pyc), gy1 = 1.f - (qrby - pyc);
            const int rx0 = (int)qltx - 1, rx1 = (int)qrbx - 1;
            const int ry0 = (int)qlty - 1, ry1 = (int)qrby - 1;
            const bool vx0 = (unsigned)rx0 < (unsigned)HH, vx1 = (unsigned)rx1 < (unsigned)HH;
            const bool vy0 = (unsigned)ry0 < (unsigned)WW, vy1 = (unsigned)ry1 < (unsigned)WW;
            const float w0 = (vx0 && vy0) ? gx0 * gy0 : 0.f;   // +0
            const float w1 = (vx1 && vy1) ? gx1 * gy1 : 0.f;   // +129
            const float w2 = (vx0 && vy1) ? gx0 * gy1 : 0.f;   // +1
            const float w3 = (vx1 && vy0) ? gx1 * gy0 : 0.f;   // +128
            mi[slot] = (short)(rx0 * WW + ry0);
            mw[slot] = make_ushort4(bfbits(w0), bfbits(w1), bfbits(w2), bfbits(w3));
        };
        mkmeta(t);
        if (t < 32) mkmeta(256 + t);
    }
    __syncthreads();

    // ---------------- independent per-wave gather + MFMA (no barriers) ----------
    const int l    = t & 63;
    const int w_   = t >> 6;
    const int sw   = w_ >> 1;          // strip within segment (0/1)
    const int half = w_ & 1;           // K half (0: k''<288, 1: >=288)
    const int r    = l & 15;
    const int kb   = l >> 4;
    const int posl = sw * 16 + r;      // 0..31
    const float* xb = x + b * (CC * HW);
    const unsigned short* wbase = Wb3 + (half * 36 + kb) * 512 + r * 8;

    f32x4 acc0 = {0.f, 0.f, 0.f, 0.f};
    f32x4 acc1 = {0.f, 0.f, 0.f, 0.f};
    f32x4 acc2 = {0.f, 0.f, 0.f, 0.f};
    f32x4 acc3 = {0.f, 0.f, 0.f, 0.f};

#pragma unroll 3
    for (int s = 0; s < 9; ++s) {
        const int a  = half * 36 + s * 4 + kb;   // k''-octet
        const int n  = a >> 3;
        const int c0 = (a & 7) * 8;
        const int slot = n * 32 + posl;
        const int base = (int)mi[slot];
        const ushort4 wq = mw[slot];
        const float w0 = frombits(wq.x), w1 = frombits(wq.y);
        const float w2 = frombits(wq.z), w3 = frombits(wq.w);
        const int i0 = iclamp(base,       0, HW - 1);
        const int i1 = iclamp(base + 129, 0, HW - 1);
        const int i2 = iclamp(base + 1,   0, HW - 1);
        const int i3 = iclamp(base + 128, 0, HW - 1);
        const float* p = xb + c0 * HW;
        bf16x8 bfrag;
#pragma unroll
        for (int j = 0; j < 8; ++j) {
            float v = p[i0] * w0;
            v = fmaf(p[i1], w1, v);
            v = fmaf(p[i2], w2, v);
            v = fmaf(p[i3], w3, v);
            bfrag[j] = (short)bfbits(v);
            p += HW;
        }
        const unsigned short* wp8 = wbase + s * 2048;
        const bf16x8 af0 = *(const bf16x8*)(wp8);
        const bf16x8 af1 = *(const bf16x8*)(wp8 + 128);
        const bf16x8 af2 = *(const bf16x8*)(wp8 + 256);
        const bf16x8 af3 = *(const bf16x8*)(wp8 + 384);
        acc0 = __builtin_amdgcn_mfma_f32_16x16x32_bf16(af0, bfrag, acc0, 0, 0, 0);
        acc1 = __builtin_amdgcn_mfma_f32_16x16x32_bf16(af1, bfrag, acc1, 0, 0, 0);
        acc2 = __builtin_amdgcn_mfma_f32_16x16x32_bf16(af2, bfrag, acc2, 0, 0, 0);
        acc3 = __builtin_amdgcn_mfma_f32_16x16x32_bf16(af3, bfrag, acc3, 0, 0, 0);
    }

    // ---------------- K-half reduction through LDS + store ----------------
    float* red = part;   // phase-0 partials dead; 2 strips x 4 tiles x 64 x 4 = 8KB
    if (half) {
        *(f32x4*)&red[sw * 1024 + 0 * 256 + l * 4] = acc0;
        *(f32x4*)&red[sw * 1024 + 1 * 256 + l * 4] = acc1;
        *(f32x4*)&red[sw * 1024 + 2 * 256 + l * 4] = acc2;
        *(f32x4*)&red[sw * 1024 + 3 * 256 + l * 4] = acc3;
    }
    __syncthreads();
    if (!half) {
        acc0 += *(const f32x4*)&red[sw * 1024 + 0 * 256 + l * 4];
        acc1 += *(const f32x4*)&red[sw * 1024 + 1 * 256 + l * 4];
        acc2 += *(const f32x4*)&red[sw * 1024 + 2 * 256 + l * 4];
        acc3 += *(const f32x4*)&red[sw * 1024 + 3 * 256 + l * 4];
        const int jcol = j0 + posl;
        f32x4 av[4] = {acc0, acc1, acc2, acc3};
#pragma unroll
        for (int m = 0; m < 4; ++m)
#pragma unroll
            for (int reg = 0; reg < 4; ++reg) {
                const int oc = m * 16 + kb * 4 + reg;
                out[((b * OC + oc) * HH + i) * WW + jcol] = av[m][reg];
            }
    }
}

// ---------------- fallback: R5 kernel (proven 116us, no workspace) ----------------

struct Meta { int i0, i1, i2, i3; float w0, w1, w2, w3; };

__device__ __forceinline__ void offset_phase(
    const float* __restrict__ x, const float* __restrict__ Wp,
    const float* __restrict__ bp, float* __restrict__ smem,
    int b, int i, int j0, int t, Meta& M0, Meta& M1)
{
    {
        const int grp = t >> 5;
        const int pp  = t & 31;
        const int j   = j0 + pp;
        float part[18];
#pragma unroll
        for (int o = 0; o < 18; ++o) part[o] = 0.f;
        const float* xg = x + (b * CC + grp * 8) * HW;
        for (int c = 0; c < 8; ++c) {
            float xv[9];
#pragma unroll
            for (int dx = 0; dx < 3; ++dx) {
                const int ii = i + dx - 1;
                const bool okx = (unsigned)ii < (unsigned)HH;
#pragma unroll
                for (int dy = 0; dy < 3; ++dy) {
                    const int jj = j + dy - 1;
                    const bool ok = okx && ((unsigned)jj < (unsigned)WW);
                    xv[dx * 3 + dy] = ok ? xg[c * HW + ii * WW + jj] : 0.f;
                }
            }
            const float* wp = Wp + (grp * 8 + c) * 9;
#pragma unroll
            for (int o = 0; o < 18; ++o) {
                const float* w = wp + o * 576;
#pragma unroll
                for (int k = 0; k < 9; ++k)
                    part[o] = fmaf(xv[k], w[k], part[o]);
            }
        }
#pragma unroll
        for (int o = 0; o < 18; ++o)
            smem[grp * 576 + pp * 18 + o] = part[o];
    }
    __syncthreads();

    auto mkmeta = [&](int pos, int n) -> Meta {
        const int kx = n / 3, ky = n - kx * 3;
        float offx = bp[n], offy = bp[9 + n];
#pragma unroll
        for (int g = 0; g < 8; ++g) {
            offx += smem[g * 576 + pos * 18 + n];
            offy += smem[g * 576 + pos * 18 + 9 + n];
        }
        const float px = offx + (float)(kx - 1) + (float)(i + 1);
        const float py = offy + (float)(ky - 1) + (float)(j0 + pos + 1);
        const float flx = floorf(px), fly = floorf(py);
        const float qltx = fminf(fmaxf(flx,       0.f), 129.f);
        const float qlty = fminf(fmaxf(fly,       0.f), 129.f);
        const float qrbx = fminf(fmaxf(flx + 1.f, 0.f), 129.f);
        const float qrby = fminf(fmaxf(fly + 1.f, 0.f), 129.f);
        const float pxc  = fminf(fmaxf(px, 0.f), 129.f);
        const float pyc  = fminf(fmaxf(py, 0.f), 129.f);
        const float gx0 = 1.f + (qltx - pxc), gx1 = 1.f - (qrbx - pxc);
        const float gy0 = 1.f + (qlty - pyc), gy1 = 1.f - (qrby - pyc);
        const int rx0 = (int)qltx - 1, rx1 = (int)qrbx - 1;
        const int ry0 = (int)qlty - 1, ry1 = (int)qrby - 1;
        const bool vx0 = (unsigned)rx0 < (unsigned)HH, vx1 = (unsigned)rx1 < (unsigned)HH;
        const bool vy0 = (unsigned)ry0 < (unsigned)WW, vy1 = (unsigned)ry1 < (unsigned)WW;
        Meta M;
        M.i0 = (vx0 && vy0) ? rx0 * WW + ry0 : 0;  M.w0 = (vx0 && vy0) ? gx0 * gy0 : 0.f;
        M.i1 = (vx1 && vy1) ? rx1 * WW + ry1 : 0;  M.w1 = (vx1 && vy1) ? gx1 * gy1 : 0.f;
        M.i2 = (vx0 && vy1) ? rx0 * WW + ry1 : 0;  M.w2 = (vx0 && vy1) ? gx0 * gy1 : 0.f;
        M.i3 = (vx1 && vy0) ? rx1 * WW + ry0 : 0;  M.w3 = (vx1 && vy0) ? gx1 * gy0 : 0.f;
        return M;
    };

    M0 = mkmeta(t & 31, t >> 5);
    M1 = mkmeta(t & 31, 8);
    __syncthreads();
}

__global__ __launch_bounds__(256, 4) void dcn_mfma(
    const float* __restrict__ x,
    const float* __restrict__ Wp,
    const float* __restrict__ bp,
    const float* __restrict__ Wc,
    float* __restrict__ out)
{
    __shared__ __align__(16) unsigned char smraw[36864];
    float* smf = (float*)smraw;
    unsigned short* bbuf = (unsigned short*)smraw;

    const int t  = threadIdx.x;
    const int bx = blockIdx.x;
    const int b  = bx >> 9;
    const int i  = (bx >> 2) & 127;
    const int j0 = (bx & 3) << 5;

    Meta M0, M1;
    offset_phase(x, Wp, bp, smf, b, i, j0, t, M0, M1);

    const int pos = t & 31;
    const int n0  = t >> 5;
    const int ccb = (t >> 5) << 2;
    const float* xb = x + b * (CC * HW);

    auto stage = [&](int ch0, int dbase) {
#pragma unroll 8
        for (int cc = 0; cc < 32; ++cc) {
            const float* p = xb + (ch0 + cc) * HW;
            float v = p[M0.i0] * M0.w0;
            v = fmaf(p[M0.i1], M0.w1, v);
            v = fmaf(p[M0.i2], M0.w2, v);
            v = fmaf(p[M0.i3], M0.w3, v);
            const int kp = cc * 9 + n0;
            bbuf[dbase + ((kp >> 3) << 8) + (pos << 3) + (kp & 7)] = bfbits(v);
        }
#pragma unroll
        for (int q = 0; q < 4; ++q) {
            const int cc = ccb + q;
            const float* p = xb + (ch0 + cc) * HW;
            float v = p[M1.i0] * M1.w0;
            v = fmaf(p[M1.i1], M1.w1, v);
            v = fmaf(p[M1.i2], M1.w2, v);
            v = fmaf(p[M1.i3], M1.w3, v);
            const int kp = cc * 9 + 8;
            bbuf[dbase + ((kp >> 3) << 8) + (pos << 3) + (kp & 7)] = bfbits(v);
        }
    };

    const int w_s = __builtin_amdgcn_readfirstlane(t >> 6);
    const int l   = t & 63;
    const int r   = l & 15;
    const int kb  = l >> 4;
    const float* arow = Wc + (w_s * 16 + r) * 576 + kb * 8;

    f32x4 acc0 = {0.f, 0.f, 0.f, 0.f};
    f32x4 acc1 = {0.f, 0.f, 0.f, 0.f};

    auto mfma_chunk = [&](int cb, int dbase) {
#pragma unroll 3
        for (int s = 0; s < 9; ++s) {
            const float* ap = arow + cb + s * 32;
            const float4 alo = *(const float4*)ap;
            const float4 ahi = *(const float4*)(ap + 4);
            bf16x8 af;
            af[0] = (short)bfbits(alo.x); af[1] = (short)bfbits(alo.y);
            af[2] = (short)bfbits(alo.z); af[3] = (short)bfbits(alo.w);
            af[4] = (short)bfbits(ahi.x); af[5] = (short)bfbits(ahi.y);
            af[6] = (short)bfbits(ahi.z); af[7] = (short)bfbits(ahi.w);
            const unsigned short* bp0 = bbuf + dbase + ((s * 4 + kb) << 8) + (r << 3);
            const bf16x8 bf0 = *(const bf16x8*)bp0;
            const bf16x8 bf1 = *(const bf16x8*)(bp0 + 128);
            acc0 = __builtin_amdgcn_mfma_f32_16x16x32_bf16(af, bf0, acc0, 0, 0, 0);
            acc1 = __builtin_amdgcn_mfma_f32_16x16x32_bf16(af, bf1, acc1, 0, 0, 0);
        }
    };

    stage(0, 0);
    __syncthreads();
    mfma_chunk(0, 0);
    stage(32, 9216);
    __syncthreads();
    mfma_chunk(288, 9216);

    const int ocb = b * OC + w_s * 16;
#pragma unroll
    for (int reg = 0; reg < 4; ++reg) {
        const int oc = ocb + (l >> 4) * 4 + reg;
        float* o = out + (oc * HH + i) * WW + j0;
        o[r]      = acc0[reg];
        o[16 + r] = acc1[reg];
    }
}

extern "C" void kernel_launch(void* const* d_in, const int* in_sizes, int n_in,
                              void* d_out, int out_size, void* d_ws, size_t ws_size,
                              hipStream_t stream) {
    const float* x  = (const float*)d_in[0];
    const float* Wp = (const float*)d_in[1];
    const float* bp = (const float*)d_in[2];
    const float* Wc = (const float*)d_in[3];
    float* out = (float*)d_out;
    if (ws_size >= (size_t)(OC * 576 * 2)) {
        unsigned short* Wb3 = (unsigned short*)d_ws;
        wpack2<<<dim3((OC * 576 + 255) / 256), dim3(256), 0, stream>>>(Wc, Wb3);
        dcn_wave<<<dim3(BB * HH * 4), dim3(256), 0, stream>>>(x, Wp, bp, Wb3, out);
    } else {
        dcn_mfma<<<dim3(BB * HH * 4), dim3(256), 0, stream>>>(x, Wp, bp, Wc, out);
    }
}